// Round 1
// baseline (858.628 us; speedup 1.0000x reference)
//
#include <hip/hip_runtime.h>
#include <cstdint>
#include <cstddef>

#define N_NODES 65536
#define N_EDGES 1048576
#define E_TOT   (N_EDGES + N_NODES)

// ---------------- preprocessing ----------------

__global__ void k_init_deg(int* __restrict__ deg) {
    int n = blockIdx.x * 256 + threadIdx.x;
    if (n < N_NODES) deg[n] = 1;  // self loop
}

__global__ void k_hist(const int* __restrict__ dst, int* __restrict__ deg) {
    int e = blockIdx.x * 256 + threadIdx.x;
    if (e < N_EDGES) atomicAdd(&deg[dst[e]], 1);
}

// single-block scan of 65536 degrees -> CSR offsets, cursor copy, dis = 1/sqrt(deg)
__global__ __launch_bounds__(1024) void k_scan(const int* __restrict__ deg, int* __restrict__ off,
                                               int* __restrict__ cursor, float* __restrict__ dis) {
    __shared__ int sb[1024];
    __shared__ int s_carry;
    int tid = threadIdx.x;
    if (tid == 0) s_carry = 0;
    __syncthreads();
    for (int base = 0; base < N_NODES; base += 1024) {
        int v = deg[base + tid];
        dis[base + tid] = 1.0f / sqrtf((float)v);
        sb[tid] = v;
        __syncthreads();
        #pragma unroll
        for (int sft = 1; sft < 1024; sft <<= 1) {
            int t = (tid >= sft) ? sb[tid - sft] : 0;
            __syncthreads();
            sb[tid] += t;
            __syncthreads();
        }
        int c = s_carry;
        int excl = c + sb[tid] - v;
        off[base + tid]    = excl;
        cursor[base + tid] = excl;
        __syncthreads();
        if (tid == 1023) s_carry = c + sb[tid];
        __syncthreads();
    }
    if (tid == 0) off[N_NODES] = s_carry;
}

// counting-sort edges by dst; store src index and norm = dis[src]*dis[dst]
__global__ void k_scatter(const int* __restrict__ src, const int* __restrict__ dst,
                          const float* __restrict__ dis, int* __restrict__ cursor,
                          int* __restrict__ ssort, float* __restrict__ nsort) {
    int e = blockIdx.x * 256 + threadIdx.x;
    if (e >= E_TOT) return;
    int s, d;
    if (e < N_EDGES) { s = src[e]; d = dst[e]; }
    else             { s = d = e - N_EDGES; }
    float w = dis[s] * dis[d];
    int pos = atomicAdd(&cursor[d], 1);
    ssort[pos] = s;
    nsort[pos] = w;
}

// ---------------- fp32 GEMM: C[M,Nd] = A[M,K] @ B[K,Nd] ----------------
// BM=BN=64, BK=16, 256 threads, 4x4 micro-tile. All dims divide evenly here.

#define BM 64
#define BN 64
#define BK 16

__global__ __launch_bounds__(256) void k_gemm(const float* __restrict__ A, const float* __restrict__ B,
                                              float* __restrict__ C, int M, int Nd, int K) {
    __shared__ float As[BK][BM];
    __shared__ float Bs[BK][BN];
    int tid = threadIdx.x;
    int tx = tid & 15, ty = tid >> 4;
    int row0 = blockIdx.y * BM, col0 = blockIdx.x * BN;
    int ar = tid >> 2;           // A tile row 0..63
    int ak = (tid & 3) * 4;      // A tile k  0,4,8,12
    int bk = tid >> 4;           // B tile k  0..15
    int bc = (tid & 15) * 4;     // B tile col 0..60
    float acc[4][4] = {};
    for (int k0 = 0; k0 < K; k0 += BK) {
        float4 av = *(const float4*)(A + (size_t)(row0 + ar) * K + k0 + ak);
        float4 bv = *(const float4*)(B + (size_t)(k0 + bk) * Nd + col0 + bc);
        __syncthreads();
        As[ak + 0][ar] = av.x; As[ak + 1][ar] = av.y;
        As[ak + 2][ar] = av.z; As[ak + 3][ar] = av.w;
        *(float4*)(&Bs[bk][bc]) = bv;
        __syncthreads();
        #pragma unroll
        for (int kk = 0; kk < BK; ++kk) {
            float4 a4 = *(const float4*)(&As[kk][ty * 4]);
            float4 b4 = *(const float4*)(&Bs[kk][tx * 4]);
            float aa[4] = {a4.x, a4.y, a4.z, a4.w};
            float bb[4] = {b4.x, b4.y, b4.z, b4.w};
            #pragma unroll
            for (int i = 0; i < 4; ++i)
                #pragma unroll
                for (int j = 0; j < 4; ++j)
                    acc[i][j] = fmaf(aa[i], bb[j], acc[i][j]);
        }
    }
    #pragma unroll
    for (int i = 0; i < 4; ++i) {
        float4 o = make_float4(acc[i][0], acc[i][1], acc[i][2], acc[i][3]);
        *(float4*)(C + (size_t)(row0 + ty * 4 + i) * Nd + col0 + tx * 4) = o;
    }
}

// ---------------- fused aggregate + bias + ReLU + row softmax ----------------
// one wave (64 lanes) per node; 4 nodes per 256-thread block.
// out[n,:] = softmax(relu(sum_{e in seg(n)} norm[e]*h[src[e],:] + bias))

template <int DOUT>
__global__ __launch_bounds__(256) void k_agg(const float* __restrict__ h, const int* __restrict__ off,
                                             const int* __restrict__ ss, const float* __restrict__ nn,
                                             const float* __restrict__ bias, float* __restrict__ out) {
    constexpr int R = DOUT / 64;
    int lane = threadIdx.x & 63;
    int n = blockIdx.x * 4 + (threadIdx.x >> 6);
    float acc[R];
    #pragma unroll
    for (int r = 0; r < R; ++r) acc[r] = 0.0f;
    int e0 = off[n], e1 = off[n + 1];
    for (int e = e0; e < e1; ++e) {
        int s = ss[e];
        float w = nn[e];
        const float* hp = h + (size_t)s * DOUT + lane;
        #pragma unroll
        for (int r = 0; r < R; ++r) acc[r] = fmaf(w, hp[64 * r], acc[r]);
    }
    float m = 0.0f;  // ReLU guarantees row max >= 0
    #pragma unroll
    for (int r = 0; r < R; ++r) {
        float v = fmaxf(acc[r] + bias[64 * r + lane], 0.0f);
        acc[r] = v;
        m = fmaxf(m, v);
    }
    #pragma unroll
    for (int sft = 32; sft > 0; sft >>= 1) m = fmaxf(m, __shfl_xor(m, sft, 64));
    float sum = 0.0f;
    #pragma unroll
    for (int r = 0; r < R; ++r) {
        float t = __expf(acc[r] - m);
        acc[r] = t;
        sum += t;
    }
    #pragma unroll
    for (int sft = 32; sft > 0; sft >>= 1) sum += __shfl_xor(sum, sft, 64);
    float inv = 1.0f / sum;
    #pragma unroll
    for (int r = 0; r < R; ++r) out[(size_t)n * DOUT + 64 * r + lane] = acc[r] * inv;
}

// ---------------- launch ----------------

extern "C" void kernel_launch(void* const* d_in, const int* in_sizes, int n_in,
                              void* d_out, int out_size, void* d_ws, size_t ws_size,
                              hipStream_t stream) {
    const float* x  = (const float*)d_in[0];
    const int*   ei = (const int*)d_in[1];
    const float* W1 = (const float*)d_in[2];
    const float* b1 = (const float*)d_in[3];
    const float* W2 = (const float*)d_in[4];
    const float* b2 = (const float*)d_in[5];
    const float* W3 = (const float*)d_in[6];
    const float* b3 = (const float*)d_in[7];
    const int* srcE = ei;
    const int* dstE = ei + N_EDGES;

    char* p = (char*)d_ws;
    auto carve = [&](size_t bytes) {
        char* q = p;
        p += (bytes + 255) & ~(size_t)255;
        return q;
    };
    int*   deg   = (int*)carve(sizeof(int) * N_NODES);
    int*   off   = (int*)carve(sizeof(int) * (N_NODES + 1));
    int*   cur   = (int*)carve(sizeof(int) * N_NODES);
    float* dis   = (float*)carve(sizeof(float) * N_NODES);
    int*   ssort = (int*)carve(sizeof(int) * E_TOT);
    float* nsort = (float*)carve(sizeof(float) * E_TOT);
    float* bufA  = (float*)carve(sizeof(float) * (size_t)N_NODES * 256);
    float* bufB  = (float*)carve(sizeof(float) * (size_t)N_NODES * 256);

    k_init_deg<<<N_NODES / 256, 256, 0, stream>>>(deg);
    k_hist<<<(N_EDGES + 255) / 256, 256, 0, stream>>>(dstE, deg);
    k_scan<<<1, 1024, 0, stream>>>(deg, off, cur, dis);
    k_scatter<<<(E_TOT + 255) / 256, 256, 0, stream>>>(srcE, dstE, dis, cur, ssort, nsort);

    // layer 1: h = x @ W1 (65536x128 @ 128x256) -> agg -> x1 (N x 256)
    k_gemm<<<dim3(256 / 64, N_NODES / 64), 256, 0, stream>>>(x, W1, bufA, N_NODES, 256, 128);
    k_agg<256><<<N_NODES / 4, 256, 0, stream>>>(bufA, off, ssort, nsort, b1, bufB);
    // layer 2: h = x1 @ W2 (65536x256 @ 256x128) -> agg -> x2 (N x 128)
    k_gemm<<<dim3(128 / 64, N_NODES / 64), 256, 0, stream>>>(bufB, W2, bufA, N_NODES, 128, 256);
    k_agg<128><<<N_NODES / 4, 256, 0, stream>>>(bufA, off, ssort, nsort, b2, bufB);
    // layer 3: h = x2 @ W3 (65536x128 @ 128x64) -> agg -> out (N x 64)
    k_gemm<<<dim3(64 / 64, N_NODES / 64), 256, 0, stream>>>(bufB, W3, bufA, N_NODES, 64, 128);
    k_agg<64><<<N_NODES / 4, 256, 0, stream>>>(bufA, off, ssort, nsort, b3, (float*)d_out);
}

// Round 2
// 622.029 us; speedup vs baseline: 1.3804x; 1.3804x over previous
//
#include <hip/hip_runtime.h>
#include <cstdint>
#include <cstddef>

#define N_NODES 65536
#define N_EDGES 1048576
#define E_TOT   (N_EDGES + N_NODES)

// ---------------- preprocessing ----------------

__global__ void k_init_deg(int* __restrict__ deg) {
    int n = blockIdx.x * 256 + threadIdx.x;
    deg[n] = 1;  // self loop
}

__global__ void k_hist(const int* __restrict__ dst, int* __restrict__ deg) {
    int e = blockIdx.x * 256 + threadIdx.x;
    if (e < N_EDGES) atomicAdd(&deg[dst[e]], 1);
}

// hierarchical exclusive scan of deg[65536] -> off, plus cursor copy and dis = rsqrt(deg)
__global__ __launch_bounds__(256) void k_scan1(const int* __restrict__ deg, int* __restrict__ off,
                                               int* __restrict__ bsum) {
    __shared__ int sb[256];
    int tid = threadIdx.x;
    int g = blockIdx.x * 256 + tid;
    int v = deg[g];
    sb[tid] = v;
    __syncthreads();
    #pragma unroll
    for (int s = 1; s < 256; s <<= 1) {
        int t = (tid >= s) ? sb[tid - s] : 0;
        __syncthreads();
        sb[tid] += t;
        __syncthreads();
    }
    off[g] = sb[tid] - v;  // exclusive within block
    if (tid == 255) bsum[blockIdx.x] = sb[255];
}

__global__ __launch_bounds__(256) void k_scan2(int* __restrict__ bsum) {
    __shared__ int sb[256];
    int tid = threadIdx.x;
    int v = bsum[tid];
    sb[tid] = v;
    __syncthreads();
    #pragma unroll
    for (int s = 1; s < 256; s <<= 1) {
        int t = (tid >= s) ? sb[tid - s] : 0;
        __syncthreads();
        sb[tid] += t;
        __syncthreads();
    }
    bsum[tid] = sb[tid] - v;  // exclusive block bases
}

__global__ __launch_bounds__(256) void k_scan3(const int* __restrict__ deg, int* __restrict__ off,
                                               int* __restrict__ cursor, float* __restrict__ dis,
                                               const int* __restrict__ bsum) {
    int tid = threadIdx.x;
    int g = blockIdx.x * 256 + tid;
    int o = off[g] + bsum[blockIdx.x];
    off[g] = o;
    cursor[g] = o;
    dis[g] = rsqrtf((float)deg[g]);
    if (g == 0) off[N_NODES] = E_TOT;  // total is fixed: every edge lands in exactly one segment
}

// counting-sort edges by dst; store src index and norm = dis[src]*dis[dst]
__global__ void k_scatter(const int* __restrict__ src, const int* __restrict__ dst,
                          const float* __restrict__ dis, int* __restrict__ cursor,
                          int* __restrict__ ssort, float* __restrict__ nsort) {
    int e = blockIdx.x * 256 + threadIdx.x;
    if (e >= E_TOT) return;
    int s, d;
    if (e < N_EDGES) { s = src[e]; d = dst[e]; }
    else             { s = d = e - N_EDGES; }
    float w = dis[s] * dis[d];
    int pos = atomicAdd(&cursor[d], 1);
    ssort[pos] = s;
    nsort[pos] = w;
}

// ---------------- fp32 GEMM: C[M,Nd] = A[M,K] @ B[K,Nd] ----------------
// BM=128, BN=64, BK=16, 256 threads, 8x4 micro-tile. All dims divide evenly here.

#define GBM 128
#define GBN 64
#define GBK 16

__global__ __launch_bounds__(256) void k_gemm(const float* __restrict__ A, const float* __restrict__ B,
                                              float* __restrict__ C, int M, int Nd, int K) {
    __shared__ float As[GBK][GBM];
    __shared__ float Bs[GBK][GBN];
    int tid = threadIdx.x;
    int tx = tid & 15;           // 0..15 -> 4 cols each
    int ty = tid >> 4;           // 0..15 -> 8 rows each
    int row0 = blockIdx.y * GBM, col0 = blockIdx.x * GBN;
    int ar = tid >> 1;           // A tile row 0..127 (2 threads per row)
    int ak = (tid & 1) * 8;      // A tile k 0 or 8
    int bk = tid >> 4;           // B tile k 0..15
    int bc = (tid & 15) * 4;     // B tile col 0..60
    float acc[8][4] = {};
    for (int k0 = 0; k0 < K; k0 += GBK) {
        const float* ap = A + (size_t)(row0 + ar) * K + k0 + ak;
        float4 a0 = *(const float4*)(ap);
        float4 a1 = *(const float4*)(ap + 4);
        float4 bv = *(const float4*)(B + (size_t)(k0 + bk) * Nd + col0 + bc);
        __syncthreads();
        As[ak + 0][ar] = a0.x; As[ak + 1][ar] = a0.y;
        As[ak + 2][ar] = a0.z; As[ak + 3][ar] = a0.w;
        As[ak + 4][ar] = a1.x; As[ak + 5][ar] = a1.y;
        As[ak + 6][ar] = a1.z; As[ak + 7][ar] = a1.w;
        *(float4*)(&Bs[bk][bc]) = bv;
        __syncthreads();
        #pragma unroll
        for (int kk = 0; kk < GBK; ++kk) {
            float4 a4lo = *(const float4*)(&As[kk][ty * 8]);
            float4 a4hi = *(const float4*)(&As[kk][ty * 8 + 4]);
            float4 b4   = *(const float4*)(&Bs[kk][tx * 4]);
            float aa[8] = {a4lo.x, a4lo.y, a4lo.z, a4lo.w, a4hi.x, a4hi.y, a4hi.z, a4hi.w};
            float bb[4] = {b4.x, b4.y, b4.z, b4.w};
            #pragma unroll
            for (int i = 0; i < 8; ++i)
                #pragma unroll
                for (int j = 0; j < 4; ++j)
                    acc[i][j] = fmaf(aa[i], bb[j], acc[i][j]);
        }
    }
    #pragma unroll
    for (int i = 0; i < 8; ++i) {
        float4 o = make_float4(acc[i][0], acc[i][1], acc[i][2], acc[i][3]);
        *(float4*)(C + (size_t)(row0 + ty * 8 + i) * Nd + col0 + tx * 4) = o;
    }
}

// ---------------- aggregation ----------------
// one wave (64 lanes) per node; 4 nodes per 256-thread block.
// ACT=true: out = softmax(relu(agg + bias)); ACT=false: out = agg (pure segment-sum)

template <int DOUT, bool ACT>
__global__ __launch_bounds__(256) void k_agg(const float* __restrict__ h, const int* __restrict__ off,
                                             const int* __restrict__ ss, const float* __restrict__ nn,
                                             const float* __restrict__ bias, float* __restrict__ out) {
    constexpr int R = DOUT / 64;
    int lane = threadIdx.x & 63;
    int n = blockIdx.x * 4 + (threadIdx.x >> 6);
    float acc[R];
    #pragma unroll
    for (int r = 0; r < R; ++r) acc[r] = 0.0f;
    int e0 = off[n], e1 = off[n + 1];
    int e = e0;
    for (; e + 2 <= e1; e += 2) {
        int s0 = ss[e], s1 = ss[e + 1];
        float w0 = nn[e], w1 = nn[e + 1];
        const float* h0 = h + (size_t)s0 * DOUT + lane;
        const float* h1 = h + (size_t)s1 * DOUT + lane;
        #pragma unroll
        for (int r = 0; r < R; ++r) {
            float v0 = h0[64 * r];
            float v1 = h1[64 * r];
            acc[r] = fmaf(w0, v0, acc[r]);
            acc[r] = fmaf(w1, v1, acc[r]);
        }
    }
    if (e < e1) {
        int s = ss[e];
        float w = nn[e];
        const float* hp = h + (size_t)s * DOUT + lane;
        #pragma unroll
        for (int r = 0; r < R; ++r) acc[r] = fmaf(w, hp[64 * r], acc[r]);
    }
    if (ACT) {
        float m = 0.0f;  // ReLU guarantees row max >= 0
        #pragma unroll
        for (int r = 0; r < R; ++r) {
            float v = fmaxf(acc[r] + bias[64 * r + lane], 0.0f);
            acc[r] = v;
            m = fmaxf(m, v);
        }
        #pragma unroll
        for (int sft = 32; sft > 0; sft >>= 1) m = fmaxf(m, __shfl_xor(m, sft, 64));
        float sum = 0.0f;
        #pragma unroll
        for (int r = 0; r < R; ++r) {
            float t = __expf(acc[r] - m);
            acc[r] = t;
            sum += t;
        }
        #pragma unroll
        for (int sft = 32; sft > 0; sft >>= 1) sum += __shfl_xor(sum, sft, 64);
        float inv = 1.0f / sum;
        #pragma unroll
        for (int r = 0; r < R; ++r) out[(size_t)n * DOUT + 64 * r + lane] = acc[r] * inv;
    } else {
        #pragma unroll
        for (int r = 0; r < R; ++r) out[(size_t)n * DOUT + 64 * r + lane] = acc[r];
    }
}

// ---------------- standalone bias + ReLU + row-softmax (layer-1 epilogue) ----------------

template <int DOUT>
__global__ __launch_bounds__(256) void k_act(const float* __restrict__ h, const float* __restrict__ bias,
                                             float* __restrict__ out) {
    constexpr int R = DOUT / 64;
    int lane = threadIdx.x & 63;
    int n = blockIdx.x * 4 + (threadIdx.x >> 6);
    float v[R];
    float m = 0.0f;
    #pragma unroll
    for (int r = 0; r < R; ++r) {
        float t = fmaxf(h[(size_t)n * DOUT + 64 * r + lane] + bias[64 * r + lane], 0.0f);
        v[r] = t;
        m = fmaxf(m, t);
    }
    #pragma unroll
    for (int sft = 32; sft > 0; sft >>= 1) m = fmaxf(m, __shfl_xor(m, sft, 64));
    float sum = 0.0f;
    #pragma unroll
    for (int r = 0; r < R; ++r) {
        float t = __expf(v[r] - m);
        v[r] = t;
        sum += t;
    }
    #pragma unroll
    for (int sft = 32; sft > 0; sft >>= 1) sum += __shfl_xor(sum, sft, 64);
    float inv = 1.0f / sum;
    #pragma unroll
    for (int r = 0; r < R; ++r) out[(size_t)n * DOUT + 64 * r + lane] = v[r] * inv;
}

// ---------------- launch ----------------

extern "C" void kernel_launch(void* const* d_in, const int* in_sizes, int n_in,
                              void* d_out, int out_size, void* d_ws, size_t ws_size,
                              hipStream_t stream) {
    const float* x  = (const float*)d_in[0];
    const int*   ei = (const int*)d_in[1];
    const float* W1 = (const float*)d_in[2];
    const float* b1 = (const float*)d_in[3];
    const float* W2 = (const float*)d_in[4];
    const float* b2 = (const float*)d_in[5];
    const float* W3 = (const float*)d_in[6];
    const float* b3 = (const float*)d_in[7];
    const int* srcE = ei;
    const int* dstE = ei + N_EDGES;

    char* p = (char*)d_ws;
    auto carve = [&](size_t bytes) {
        char* q = p;
        p += (bytes + 255) & ~(size_t)255;
        return q;
    };
    int*   deg   = (int*)carve(sizeof(int) * N_NODES);
    int*   off   = (int*)carve(sizeof(int) * (N_NODES + 1));
    int*   cur   = (int*)carve(sizeof(int) * N_NODES);
    float* dis   = (float*)carve(sizeof(float) * N_NODES);
    int*   bsum  = (int*)carve(sizeof(int) * 256);
    int*   ssort = (int*)carve(sizeof(int) * E_TOT);
    float* nsort = (float*)carve(sizeof(float) * E_TOT);
    float* bufA  = (float*)carve(sizeof(float) * (size_t)N_NODES * 256);
    float* bufB  = (float*)carve(sizeof(float) * (size_t)N_NODES * 256);

    k_init_deg<<<N_NODES / 256, 256, 0, stream>>>(deg);
    k_hist<<<(N_EDGES + 255) / 256, 256, 0, stream>>>(dstE, deg);
    k_scan1<<<N_NODES / 256, 256, 0, stream>>>(deg, off, bsum);
    k_scan2<<<1, 256, 0, stream>>>(bsum);
    k_scan3<<<N_NODES / 256, 256, 0, stream>>>(deg, off, cur, dis, bsum);
    k_scatter<<<(E_TOT + 255) / 256, 256, 0, stream>>>(srcE, dstE, dis, cur, ssort, nsort);

    // layer 1 (agg-first: segsum(x@W1) == segsum(x)@W1):
    //   a0 = segsum(x[src]*norm)          N x 128
    //   h1 = a0 @ W1                      N x 256
    //   x1 = softmax(relu(h1 + b1))       N x 256
    k_agg<128, false><<<N_NODES / 4, 256, 0, stream>>>(x, off, ssort, nsort, nullptr, bufB);
    k_gemm<<<dim3(256 / GBN, N_NODES / GBM), 256, 0, stream>>>(bufB, W1, bufA, N_NODES, 256, 128);
    k_act<256><<<N_NODES / 4, 256, 0, stream>>>(bufA, b1, bufB);
    // layer 2 (transform-first): h2 = x1 @ W2 (N x 128), x2 = softmax(relu(segsum(h2)+b2))
    k_gemm<<<dim3(128 / GBN, N_NODES / GBM), 256, 0, stream>>>(bufB, W2, bufA, N_NODES, 128, 256);
    k_agg<128, true><<<N_NODES / 4, 256, 0, stream>>>(bufA, off, ssort, nsort, b2, bufB);
    // layer 3 (transform-first): h3 = x2 @ W3 (N x 64), out = softmax(relu(segsum(h3)+b3))
    k_gemm<<<dim3(64 / GBN, N_NODES / GBM), 256, 0, stream>>>(bufB, W3, bufA, N_NODES, 64, 128);
    k_agg<64, true><<<N_NODES / 4, 256, 0, stream>>>(bufA, off, ssort, nsort, b3, (float*)d_out);
}

// Round 3
// 503.866 us; speedup vs baseline: 1.7041x; 1.2345x over previous
//
#include <hip/hip_runtime.h>
#include <cstdint>
#include <cstddef>

#define N_NODES 65536
#define N_EDGES 1048576
#define E_TOT   (N_EDGES + N_NODES)

using short8  = __attribute__((ext_vector_type(8))) short;
using floatx4 = __attribute__((ext_vector_type(4))) float;

// split fp32 -> bf16 hi (RTN) + bf16 lo (trunc of residual)
__device__ inline void split_bf16(float a, short& hi, short& lo) {
    unsigned u  = __float_as_uint(a);
    unsigned hr = (u + 0x7fffu + ((u >> 16) & 1u)) >> 16;
    float    hf = __uint_as_float(hr << 16);
    hi = (short)hr;
    float    lf = a - hf;
    lo = (short)(__float_as_uint(lf) >> 16);
}

// ---------------- preprocessing ----------------

__global__ void k_init_deg(int* __restrict__ deg) {
    int n = blockIdx.x * 256 + threadIdx.x;
    deg[n] = 1;  // self loop
}

__global__ void k_hist(const int* __restrict__ dst, int* __restrict__ deg) {
    int e = blockIdx.x * 256 + threadIdx.x;
    if (e < N_EDGES) atomicAdd(&deg[dst[e]], 1);
}

__global__ __launch_bounds__(256) void k_scan1(const int* __restrict__ deg, int* __restrict__ off,
                                               int* __restrict__ bsum) {
    __shared__ int sb[256];
    int tid = threadIdx.x;
    int g = blockIdx.x * 256 + tid;
    int v = deg[g];
    sb[tid] = v;
    __syncthreads();
    #pragma unroll
    for (int s = 1; s < 256; s <<= 1) {
        int t = (tid >= s) ? sb[tid - s] : 0;
        __syncthreads();
        sb[tid] += t;
        __syncthreads();
    }
    off[g] = sb[tid] - v;
    if (tid == 255) bsum[blockIdx.x] = sb[255];
}

__global__ __launch_bounds__(256) void k_scan2(int* __restrict__ bsum) {
    __shared__ int sb[256];
    int tid = threadIdx.x;
    int v = bsum[tid];
    sb[tid] = v;
    __syncthreads();
    #pragma unroll
    for (int s = 1; s < 256; s <<= 1) {
        int t = (tid >= s) ? sb[tid - s] : 0;
        __syncthreads();
        sb[tid] += t;
        __syncthreads();
    }
    bsum[tid] = sb[tid] - v;
}

__global__ __launch_bounds__(256) void k_scan3(const int* __restrict__ deg, int* __restrict__ off,
                                               int* __restrict__ cursor, float* __restrict__ dis,
                                               const int* __restrict__ bsum) {
    int tid = threadIdx.x;
    int g = blockIdx.x * 256 + tid;
    int o = off[g] + bsum[blockIdx.x];
    off[g] = o;
    cursor[g] = o;
    dis[g] = rsqrtf((float)deg[g]);
    if (g == 0) off[N_NODES] = E_TOT;
}

// counting-sort edges by dst; single 8B store per edge: (src, norm bits)
__global__ void k_scatter(const int* __restrict__ src, const int* __restrict__ dst,
                          const float* __restrict__ dis, int* __restrict__ cursor,
                          int2* __restrict__ edata) {
    int e = blockIdx.x * 256 + threadIdx.x;
    if (e >= E_TOT) return;
    int s, d;
    if (e < N_EDGES) { s = src[e]; d = dst[e]; }
    else             { s = d = e - N_EDGES; }
    float w = dis[s] * dis[d];
    int pos = atomicAdd(&cursor[d], 1);
    edata[pos] = make_int2(s, __float_as_int(w));
}

// ---------------- W -> fragment-ordered bf16 hi/lo ----------------
// frag order: chunk g = (nt*(K/32) + kt)*64 + lane; element j: k = kt*32 + (lane>>4)*8 + j,
// n = nt*16 + (lane&15). Lane's 8 bf16 = one short8 at [g*8].

__global__ void k_convw(const float* __restrict__ W, int K, int N,
                        short* __restrict__ Bh, short* __restrict__ Bl) {
    int g = blockIdx.x * 256 + threadIdx.x;
    int total = (N / 16) * (K / 32) * 64;
    if (g >= total) return;
    int lane = g & 63;
    int kt = (g >> 6) % (K / 32);
    int nt = (g >> 6) / (K / 32);
    int n = nt * 16 + (lane & 15);
    int kbase = kt * 32 + (lane >> 4) * 8;
    #pragma unroll
    for (int j = 0; j < 8; ++j) {
        short h, l;
        split_bf16(W[(size_t)(kbase + j) * N + n], h, l);
        Bh[(size_t)g * 8 + j] = h;
        Bl[(size_t)g * 8 + j] = l;
    }
}

// ---------------- split-bf16 MFMA GEMM: C[M,N] = A[M,K] @ W ----------------
// block = 256 threads (4 waves), tile = 64 rows x full N. wave w -> rows 16w..16w+15.
// C ~= Ah*Wh + Ah*Wl + Al*Wh via mfma_f32_16x16x32_bf16.
// ACT: C = softmax(relu(C + bias)) per row (fused epilogue).

template <int K, int N, bool ACT>
__global__ __launch_bounds__(256) void k_mm(const float* __restrict__ A,
                                            const short* __restrict__ Bh, const short* __restrict__ Bl,
                                            const float* __restrict__ bias, float* __restrict__ C) {
    constexpr int NT = N / 16;
    constexpr int KT = K / 32;
    __shared__ short Ah[4 * 64 * 8];
    __shared__ short Al[4 * 64 * 8];
    int tid = threadIdx.x;
    int wave = tid >> 6, lane = tid & 63;
    int quad = lane >> 4, col = lane & 15;
    size_t row0 = (size_t)blockIdx.x * 64;

    floatx4 acc[NT];
    #pragma unroll
    for (int t = 0; t < NT; ++t) acc[t] = (floatx4)0.0f;

    // staging map: thread t loads A[row0 + (t>>2)][kt*32 + (t&3)*8 .. +7]
    int srow = tid >> 2;
    int sk0 = (tid & 3) * 8;
    int sdst = ((srow >> 4) * 64 + (srow & 15) + ((tid & 3) << 4)) * 8;  // short index
    const float* arow = A + (row0 + srow) * K + sk0;

    for (int kt = 0; kt < KT; ++kt) {
        float4 a0 = *(const float4*)(arow + kt * 32);
        float4 a1 = *(const float4*)(arow + kt * 32 + 4);
        float av[8] = {a0.x, a0.y, a0.z, a0.w, a1.x, a1.y, a1.z, a1.w};
        short h[8], l[8];
        #pragma unroll
        for (int j = 0; j < 8; ++j) split_bf16(av[j], h[j], l[j]);
        __syncthreads();
        *(short8*)(&Ah[sdst]) = *(short8*)h;
        *(short8*)(&Al[sdst]) = *(short8*)l;
        __syncthreads();
        short8 afh = *(short8*)(&Ah[(wave * 64 + lane) * 8]);
        short8 afl = *(short8*)(&Al[(wave * 64 + lane) * 8]);
        #pragma unroll
        for (int nt = 0; nt < NT; ++nt) {
            size_t bi = ((size_t)(nt * KT + kt) * 64 + lane);
            short8 bfh = ((const short8*)Bh)[bi];
            short8 bfl = ((const short8*)Bl)[bi];
            acc[nt] = __builtin_amdgcn_mfma_f32_16x16x32_bf16(afh, bfh, acc[nt], 0, 0, 0);
            acc[nt] = __builtin_amdgcn_mfma_f32_16x16x32_bf16(afh, bfl, acc[nt], 0, 0, 0);
            acc[nt] = __builtin_amdgcn_mfma_f32_16x16x32_bf16(afl, bfh, acc[nt], 0, 0, 0);
        }
    }

    // D layout: row_in_tile = quad*4 + reg, col_in_tile = lane&15
    size_t rbase = row0 + wave * 16 + quad * 4;
    if (!ACT) {
        #pragma unroll
        for (int nt = 0; nt < NT; ++nt)
            #pragma unroll
            for (int r = 0; r < 4; ++r)
                C[(rbase + r) * N + nt * 16 + col] = acc[nt][r];
    } else {
        float bv[NT];
        #pragma unroll
        for (int nt = 0; nt < NT; ++nt) bv[nt] = bias[nt * 16 + col];
        float mr[4] = {0.f, 0.f, 0.f, 0.f};  // relu -> max >= 0
        #pragma unroll
        for (int nt = 0; nt < NT; ++nt)
            #pragma unroll
            for (int r = 0; r < 4; ++r) {
                float v = fmaxf(acc[nt][r] + bv[nt], 0.0f);
                acc[nt][r] = v;
                mr[r] = fmaxf(mr[r], v);
            }
        #pragma unroll
        for (int mask = 1; mask < 16; mask <<= 1)
            #pragma unroll
            for (int r = 0; r < 4; ++r) mr[r] = fmaxf(mr[r], __shfl_xor(mr[r], mask, 64));
        float sr[4] = {0.f, 0.f, 0.f, 0.f};
        #pragma unroll
        for (int nt = 0; nt < NT; ++nt)
            #pragma unroll
            for (int r = 0; r < 4; ++r) {
                float t = __expf(acc[nt][r] - mr[r]);
                acc[nt][r] = t;
                sr[r] += t;
            }
        #pragma unroll
        for (int mask = 1; mask < 16; mask <<= 1)
            #pragma unroll
            for (int r = 0; r < 4; ++r) sr[r] += __shfl_xor(sr[r], mask, 64);
        float inv[4];
        #pragma unroll
        for (int r = 0; r < 4; ++r) inv[r] = 1.0f / sr[r];
        #pragma unroll
        for (int nt = 0; nt < NT; ++nt)
            #pragma unroll
            for (int r = 0; r < 4; ++r)
                C[(rbase + r) * N + nt * 16 + col] = acc[nt][r] * inv[r];
    }
}

// ---------------- aggregation ----------------
// one wave per node; lane covers R contiguous cols at R*lane.
// ACT: out = softmax(relu(agg + bias)); else pure segment-sum.

template <int DOUT, bool ACT>
__global__ __launch_bounds__(256) void k_agg(const float* __restrict__ h, const int* __restrict__ off,
                                             const int2* __restrict__ ed, const float* __restrict__ bias,
                                             float* __restrict__ out) {
    constexpr int R = DOUT / 64;
    int lane = threadIdx.x & 63;
    int n = blockIdx.x * 4 + (threadIdx.x >> 6);
    int e0 = off[n], e1 = off[n + 1];
    int e = e0;
    float acc[R];
    #pragma unroll
    for (int r = 0; r < R; ++r) acc[r] = 0.0f;

    if (R == 2) {
        float2 a = make_float2(0.f, 0.f);
        for (; e + 4 <= e1; e += 4) {
            int2 p0 = ed[e], p1 = ed[e + 1], p2 = ed[e + 2], p3 = ed[e + 3];
            float2 v0 = *(const float2*)(h + (size_t)p0.x * DOUT + 2 * lane);
            float2 v1 = *(const float2*)(h + (size_t)p1.x * DOUT + 2 * lane);
            float2 v2 = *(const float2*)(h + (size_t)p2.x * DOUT + 2 * lane);
            float2 v3 = *(const float2*)(h + (size_t)p3.x * DOUT + 2 * lane);
            float w0 = __int_as_float(p0.y), w1 = __int_as_float(p1.y);
            float w2 = __int_as_float(p2.y), w3 = __int_as_float(p3.y);
            a.x = fmaf(w0, v0.x, a.x); a.y = fmaf(w0, v0.y, a.y);
            a.x = fmaf(w1, v1.x, a.x); a.y = fmaf(w1, v1.y, a.y);
            a.x = fmaf(w2, v2.x, a.x); a.y = fmaf(w2, v2.y, a.y);
            a.x = fmaf(w3, v3.x, a.x); a.y = fmaf(w3, v3.y, a.y);
        }
        for (; e < e1; ++e) {
            int2 p = ed[e];
            float w = __int_as_float(p.y);
            float2 v = *(const float2*)(h + (size_t)p.x * DOUT + 2 * lane);
            a.x = fmaf(w, v.x, a.x);
            a.y = fmaf(w, v.y, a.y);
        }
        acc[0] = a.x;
        if (R > 1) acc[1] = a.y;
    } else {
        for (; e + 4 <= e1; e += 4) {
            int2 p0 = ed[e], p1 = ed[e + 1], p2 = ed[e + 2], p3 = ed[e + 3];
            float v0 = h[(size_t)p0.x * DOUT + lane];
            float v1 = h[(size_t)p1.x * DOUT + lane];
            float v2 = h[(size_t)p2.x * DOUT + lane];
            float v3 = h[(size_t)p3.x * DOUT + lane];
            acc[0] = fmaf(__int_as_float(p0.y), v0, acc[0]);
            acc[0] = fmaf(__int_as_float(p1.y), v1, acc[0]);
            acc[0] = fmaf(__int_as_float(p2.y), v2, acc[0]);
            acc[0] = fmaf(__int_as_float(p3.y), v3, acc[0]);
        }
        for (; e < e1; ++e) {
            int2 p = ed[e];
            acc[0] = fmaf(__int_as_float(p.y), h[(size_t)p.x * DOUT + lane], acc[0]);
        }
    }

    int cbase = (R == 2) ? 2 * lane : lane;
    if (ACT) {
        float m = 0.0f;
        #pragma unroll
        for (int r = 0; r < R; ++r) {
            float v = fmaxf(acc[r] + bias[cbase + r], 0.0f);
            acc[r] = v;
            m = fmaxf(m, v);
        }
        #pragma unroll
        for (int sft = 32; sft > 0; sft >>= 1) m = fmaxf(m, __shfl_xor(m, sft, 64));
        float sum = 0.0f;
        #pragma unroll
        for (int r = 0; r < R; ++r) {
            float t = __expf(acc[r] - m);
            acc[r] = t;
            sum += t;
        }
        #pragma unroll
        for (int sft = 32; sft > 0; sft >>= 1) sum += __shfl_xor(sum, sft, 64);
        float inv = 1.0f / sum;
        #pragma unroll
        for (int r = 0; r < R; ++r) out[(size_t)n * DOUT + cbase + r] = acc[r] * inv;
    } else {
        #pragma unroll
        for (int r = 0; r < R; ++r) out[(size_t)n * DOUT + cbase + r] = acc[r];
    }
}

// ---------------- launch ----------------

extern "C" void kernel_launch(void* const* d_in, const int* in_sizes, int n_in,
                              void* d_out, int out_size, void* d_ws, size_t ws_size,
                              hipStream_t stream) {
    const float* x  = (const float*)d_in[0];
    const int*   ei = (const int*)d_in[1];
    const float* W1 = (const float*)d_in[2];
    const float* b1 = (const float*)d_in[3];
    const float* W2 = (const float*)d_in[4];
    const float* b2 = (const float*)d_in[5];
    const float* W3 = (const float*)d_in[6];
    const float* b3 = (const float*)d_in[7];
    const int* srcE = ei;
    const int* dstE = ei + N_EDGES;

    char* p = (char*)d_ws;
    auto carve = [&](size_t bytes) {
        char* q = p;
        p += (bytes + 255) & ~(size_t)255;
        return q;
    };
    int*   deg   = (int*)carve(sizeof(int) * N_NODES);
    int*   off   = (int*)carve(sizeof(int) * (N_NODES + 1));
    int*   cur   = (int*)carve(sizeof(int) * N_NODES);
    float* dis   = (float*)carve(sizeof(float) * N_NODES);
    int*   bsum  = (int*)carve(sizeof(int) * 256);
    int2*  edata = (int2*)carve(sizeof(int2) * E_TOT);
    short* w1h   = (short*)carve(sizeof(short) * 128 * 256);
    short* w1l   = (short*)carve(sizeof(short) * 128 * 256);
    short* w2h   = (short*)carve(sizeof(short) * 256 * 128);
    short* w2l   = (short*)carve(sizeof(short) * 256 * 128);
    short* w3h   = (short*)carve(sizeof(short) * 128 * 64);
    short* w3l   = (short*)carve(sizeof(short) * 128 * 64);
    float* bufA  = (float*)carve(sizeof(float) * (size_t)N_NODES * 256);
    float* bufB  = (float*)carve(sizeof(float) * (size_t)N_NODES * 256);

    k_init_deg<<<N_NODES / 256, 256, 0, stream>>>(deg);
    k_hist<<<(N_EDGES + 255) / 256, 256, 0, stream>>>(dstE, deg);
    k_scan1<<<N_NODES / 256, 256, 0, stream>>>(deg, off, bsum);
    k_scan2<<<1, 256, 0, stream>>>(bsum);
    k_scan3<<<N_NODES / 256, 256, 0, stream>>>(deg, off, cur, dis, bsum);
    k_scatter<<<(E_TOT + 255) / 256, 256, 0, stream>>>(srcE, dstE, dis, cur, edata);
    k_convw<<<(16 * 4 * 64 + 255) / 256, 256, 0, stream>>>(W1, 128, 256, w1h, w1l);
    k_convw<<<(8 * 8 * 64 + 255) / 256, 256, 0, stream>>>(W2, 256, 128, w2h, w2l);
    k_convw<<<(4 * 4 * 64 + 255) / 256, 256, 0, stream>>>(W3, 128, 64, w3h, w3l);

    // layer 1 (agg-first): a0 = segsum(x[src]*norm); x1 = softmax(relu(a0@W1 + b1))
    k_agg<128, false><<<N_NODES / 4, 256, 0, stream>>>(x, off, edata, nullptr, bufB);
    k_mm<128, 256, true><<<N_NODES / 64, 256, 0, stream>>>(bufB, w1h, w1l, b1, bufA);
    // layer 2 (transform-first): h2 = x1@W2; x2 = softmax(relu(segsum(h2) + b2))
    k_mm<256, 128, false><<<N_NODES / 64, 256, 0, stream>>>(bufA, w2h, w2l, nullptr, bufB);
    k_agg<128, true><<<N_NODES / 4, 256, 0, stream>>>(bufB, off, edata, b2, bufA);
    // layer 3 (transform-first): h3 = x2@W3; out = softmax(relu(segsum(h3) + b3))
    k_mm<128, 64, false><<<N_NODES / 64, 256, 0, stream>>>(bufA, w3h, w3l, nullptr, bufB);
    k_agg<64, true><<<N_NODES / 4, 256, 0, stream>>>(bufB, off, edata, b3, (float*)d_out);
}

// Round 4
// 500.882 us; speedup vs baseline: 1.7142x; 1.0060x over previous
//
#include <hip/hip_runtime.h>
#include <cstdint>
#include <cstddef>

#define N_NODES 65536
#define N_EDGES 1048576
#define E_TOT   (N_EDGES + N_NODES)

using short8  = __attribute__((ext_vector_type(8))) short;
using floatx4 = __attribute__((ext_vector_type(4))) float;

// split fp32 -> bf16 hi (RTN) + bf16 lo (trunc of residual)
__device__ inline void split_bf16(float a, short& hi, short& lo) {
    unsigned u  = __float_as_uint(a);
    unsigned hr = (u + 0x7fffu + ((u >> 16) & 1u)) >> 16;
    float    hf = __uint_as_float(hr << 16);
    hi = (short)hr;
    float    lf = a - hf;
    lo = (short)(__float_as_uint(lf) >> 16);
}

// ---------------- preprocessing ----------------

__global__ void k_init_deg(int* __restrict__ deg) {
    int n = blockIdx.x * 256 + threadIdx.x;
    deg[n] = 1;  // self loop
}

__global__ void k_hist(const int* __restrict__ dst, int* __restrict__ deg) {
    int e = blockIdx.x * 256 + threadIdx.x;
    if (e < N_EDGES) atomicAdd(&deg[dst[e]], 1);
}

__global__ __launch_bounds__(256) void k_scan1(const int* __restrict__ deg, int* __restrict__ off,
                                               int* __restrict__ bsum) {
    __shared__ int sb[256];
    int tid = threadIdx.x;
    int g = blockIdx.x * 256 + tid;
    int v = deg[g];
    sb[tid] = v;
    __syncthreads();
    #pragma unroll
    for (int s = 1; s < 256; s <<= 1) {
        int t = (tid >= s) ? sb[tid - s] : 0;
        __syncthreads();
        sb[tid] += t;
        __syncthreads();
    }
    off[g] = sb[tid] - v;
    if (tid == 255) bsum[blockIdx.x] = sb[255];
}

__global__ __launch_bounds__(256) void k_scan2(int* __restrict__ bsum) {
    __shared__ int sb[256];
    int tid = threadIdx.x;
    int v = bsum[tid];
    sb[tid] = v;
    __syncthreads();
    #pragma unroll
    for (int s = 1; s < 256; s <<= 1) {
        int t = (tid >= s) ? sb[tid - s] : 0;
        __syncthreads();
        sb[tid] += t;
        __syncthreads();
    }
    bsum[tid] = sb[tid] - v;
}

__global__ __launch_bounds__(256) void k_scan3(const int* __restrict__ deg, int* __restrict__ off,
                                               int* __restrict__ cursor, float* __restrict__ dis,
                                               const int* __restrict__ bsum) {
    int tid = threadIdx.x;
    int g = blockIdx.x * 256 + tid;
    int o = off[g] + bsum[blockIdx.x];
    off[g] = o;
    cursor[g] = o;
    dis[g] = rsqrtf((float)deg[g]);
    if (g == 0) off[N_NODES] = E_TOT;
}

// counting-sort edges by dst; store src index only (norm is factored into dis[src]/dis[dst])
__global__ void k_scatter(const int* __restrict__ src, const int* __restrict__ dst,
                          int* __restrict__ cursor, int* __restrict__ ssort) {
    int e = blockIdx.x * 256 + threadIdx.x;
    if (e >= E_TOT) return;
    int s, d;
    if (e < N_EDGES) { s = src[e]; d = dst[e]; }
    else             { s = d = e - N_EDGES; }
    int pos = atomicAdd(&cursor[d], 1);
    ssort[pos] = s;
}

// ---------------- W -> fragment-ordered bf16 hi/lo ----------------

__global__ void k_convw(const float* __restrict__ W, int K, int N,
                        short* __restrict__ Bh, short* __restrict__ Bl) {
    int g = blockIdx.x * 256 + threadIdx.x;
    int total = (N / 16) * (K / 32) * 64;
    if (g >= total) return;
    int lane = g & 63;
    int kt = (g >> 6) % (K / 32);
    int nt = (g >> 6) / (K / 32);
    int n = nt * 16 + (lane & 15);
    int kbase = kt * 32 + (lane >> 4) * 8;
    #pragma unroll
    for (int j = 0; j < 8; ++j) {
        short h, l;
        split_bf16(W[(size_t)(kbase + j) * N + n], h, l);
        Bh[(size_t)g * 8 + j] = h;
        Bl[(size_t)g * 8 + j] = l;
    }
}

// ---------------- split-bf16 MFMA GEMM: C[M,N] = A[M,K] @ W ----------------
// ACT: C = softmax(relu(C + bias)) per row.
// SCALE_OUT: C row r scaled by dis[r] (prepares rows for dis-factored aggregation).

template <int K, int N, bool ACT, bool SCALE_OUT>
__global__ __launch_bounds__(256) void k_mm(const float* __restrict__ A,
                                            const short* __restrict__ Bh, const short* __restrict__ Bl,
                                            const float* __restrict__ bias, const float* __restrict__ dis,
                                            float* __restrict__ C) {
    constexpr int NT = N / 16;
    constexpr int KT = K / 32;
    __shared__ short Ah[4 * 64 * 8];
    __shared__ short Al[4 * 64 * 8];
    int tid = threadIdx.x;
    int wave = tid >> 6, lane = tid & 63;
    int quad = lane >> 4, col = lane & 15;
    size_t row0 = (size_t)blockIdx.x * 64;

    floatx4 acc[NT];
    #pragma unroll
    for (int t = 0; t < NT; ++t) acc[t] = (floatx4)0.0f;

    int srow = tid >> 2;
    int sdst = ((srow >> 4) * 64 + (srow & 15) + ((tid & 3) << 4)) * 8;
    const float* arow = A + (row0 + srow) * K + (tid & 3) * 8;

    for (int kt = 0; kt < KT; ++kt) {
        float4 a0 = *(const float4*)(arow + kt * 32);
        float4 a1 = *(const float4*)(arow + kt * 32 + 4);
        float av[8] = {a0.x, a0.y, a0.z, a0.w, a1.x, a1.y, a1.z, a1.w};
        short h[8], l[8];
        #pragma unroll
        for (int j = 0; j < 8; ++j) split_bf16(av[j], h[j], l[j]);
        __syncthreads();
        *(short8*)(&Ah[sdst]) = *(short8*)h;
        *(short8*)(&Al[sdst]) = *(short8*)l;
        __syncthreads();
        short8 afh = *(short8*)(&Ah[(wave * 64 + lane) * 8]);
        short8 afl = *(short8*)(&Al[(wave * 64 + lane) * 8]);
        #pragma unroll
        for (int nt = 0; nt < NT; ++nt) {
            size_t bi = ((size_t)(nt * KT + kt) * 64 + lane);
            short8 bfh = ((const short8*)Bh)[bi];
            short8 bfl = ((const short8*)Bl)[bi];
            acc[nt] = __builtin_amdgcn_mfma_f32_16x16x32_bf16(afh, bfh, acc[nt], 0, 0, 0);
            acc[nt] = __builtin_amdgcn_mfma_f32_16x16x32_bf16(afh, bfl, acc[nt], 0, 0, 0);
            acc[nt] = __builtin_amdgcn_mfma_f32_16x16x32_bf16(afl, bfh, acc[nt], 0, 0, 0);
        }
    }

    size_t rbase = row0 + wave * 16 + quad * 4;
    if (!ACT) {
        float4 d4 = make_float4(1.f, 1.f, 1.f, 1.f);
        if (SCALE_OUT) d4 = *(const float4*)(dis + rbase);
        float dr[4] = {d4.x, d4.y, d4.z, d4.w};
        #pragma unroll
        for (int nt = 0; nt < NT; ++nt)
            #pragma unroll
            for (int r = 0; r < 4; ++r)
                C[(rbase + r) * N + nt * 16 + col] = acc[nt][r] * dr[r];
    } else {
        float bv[NT];
        #pragma unroll
        for (int nt = 0; nt < NT; ++nt) bv[nt] = bias[nt * 16 + col];
        float mr[4] = {0.f, 0.f, 0.f, 0.f};
        #pragma unroll
        for (int nt = 0; nt < NT; ++nt)
            #pragma unroll
            for (int r = 0; r < 4; ++r) {
                float v = fmaxf(acc[nt][r] + bv[nt], 0.0f);
                acc[nt][r] = v;
                mr[r] = fmaxf(mr[r], v);
            }
        #pragma unroll
        for (int mask = 1; mask < 16; mask <<= 1)
            #pragma unroll
            for (int r = 0; r < 4; ++r) mr[r] = fmaxf(mr[r], __shfl_xor(mr[r], mask, 64));
        float sr[4] = {0.f, 0.f, 0.f, 0.f};
        #pragma unroll
        for (int nt = 0; nt < NT; ++nt)
            #pragma unroll
            for (int r = 0; r < 4; ++r) {
                float t = __expf(acc[nt][r] - mr[r]);
                acc[nt][r] = t;
                sr[r] += t;
            }
        #pragma unroll
        for (int mask = 1; mask < 16; mask <<= 1)
            #pragma unroll
            for (int r = 0; r < 4; ++r) sr[r] += __shfl_xor(sr[r], mask, 64);
        float inv[4];
        #pragma unroll
        for (int r = 0; r < 4; ++r) inv[r] = 1.0f / sr[r];
        #pragma unroll
        for (int nt = 0; nt < NT; ++nt)
            #pragma unroll
            for (int r = 0; r < 4; ++r)
                C[(rbase + r) * N + nt * 16 + col] = acc[nt][r] * inv[r];
    }
}

// ---------------- aggregation, DOUT=128: half-wave (32 lanes x float4) per edge ----------------
// out_pre[n] = dis[n] * sum_e g(src_e), where g = dis[s]*h[s] (SCALE_SRC) or pre-scaled h' rows.
// ACT: out = softmax(relu(out_pre + bias)); else out = out_pre.

template <bool SCALE_SRC, bool ACT>
__global__ __launch_bounds__(256) void k_agg128(const float* __restrict__ h, const int* __restrict__ off,
                                                const int* __restrict__ ss, const float* __restrict__ dis,
                                                const float* __restrict__ bias, float* __restrict__ out) {
    int lane = threadIdx.x & 63;
    int half = lane >> 5;
    int li = lane & 31;
    int c0 = 4 * li;
    int n = blockIdx.x * 4 + (threadIdx.x >> 6);
    int e0 = off[n], e1 = off[n + 1];
    int e = e0;
    float4 acc = make_float4(0.f, 0.f, 0.f, 0.f);

    // 8 edges per iter: 4 pairs, half-wave per edge
    for (; e + 8 <= e1; e += 8) {
        int s0 = ss[e + 0 + half];
        int s1 = ss[e + 2 + half];
        int s2 = ss[e + 4 + half];
        int s3 = ss[e + 6 + half];
        float4 v0 = *(const float4*)(h + (size_t)s0 * 128 + c0);
        float4 v1 = *(const float4*)(h + (size_t)s1 * 128 + c0);
        float4 v2 = *(const float4*)(h + (size_t)s2 * 128 + c0);
        float4 v3 = *(const float4*)(h + (size_t)s3 * 128 + c0);
        float w0 = SCALE_SRC ? dis[s0] : 1.0f;
        float w1 = SCALE_SRC ? dis[s1] : 1.0f;
        float w2 = SCALE_SRC ? dis[s2] : 1.0f;
        float w3 = SCALE_SRC ? dis[s3] : 1.0f;
        acc.x = fmaf(w0, v0.x, acc.x); acc.y = fmaf(w0, v0.y, acc.y);
        acc.z = fmaf(w0, v0.z, acc.z); acc.w = fmaf(w0, v0.w, acc.w);
        acc.x = fmaf(w1, v1.x, acc.x); acc.y = fmaf(w1, v1.y, acc.y);
        acc.z = fmaf(w1, v1.z, acc.z); acc.w = fmaf(w1, v1.w, acc.w);
        acc.x = fmaf(w2, v2.x, acc.x); acc.y = fmaf(w2, v2.y, acc.y);
        acc.z = fmaf(w2, v2.z, acc.z); acc.w = fmaf(w2, v2.w, acc.w);
        acc.x = fmaf(w3, v3.x, acc.x); acc.y = fmaf(w3, v3.y, acc.y);
        acc.z = fmaf(w3, v3.z, acc.z); acc.w = fmaf(w3, v3.w, acc.w);
    }
    for (; e + 2 <= e1; e += 2) {
        int s = ss[e + half];
        float4 v = *(const float4*)(h + (size_t)s * 128 + c0);
        float w = SCALE_SRC ? dis[s] : 1.0f;
        acc.x = fmaf(w, v.x, acc.x); acc.y = fmaf(w, v.y, acc.y);
        acc.z = fmaf(w, v.z, acc.z); acc.w = fmaf(w, v.w, acc.w);
    }
    if (e < e1) {  // odd tail: only half 0 contributes
        int s = ss[e];
        float4 v = *(const float4*)(h + (size_t)s * 128 + c0);
        float w = (half == 0) ? (SCALE_SRC ? dis[s] : 1.0f) : 0.0f;
        acc.x = fmaf(w, v.x, acc.x); acc.y = fmaf(w, v.y, acc.y);
        acc.z = fmaf(w, v.z, acc.z); acc.w = fmaf(w, v.w, acc.w);
    }

    // combine halves (both halves end up with the full sum)
    acc.x += __shfl_xor(acc.x, 32, 64);
    acc.y += __shfl_xor(acc.y, 32, 64);
    acc.z += __shfl_xor(acc.z, 32, 64);
    acc.w += __shfl_xor(acc.w, 32, 64);

    float dn = dis[n];
    acc.x *= dn; acc.y *= dn; acc.z *= dn; acc.w *= dn;

    if (ACT) {
        float4 b4 = *(const float4*)(bias + c0);
        float v[4] = {fmaxf(acc.x + b4.x, 0.f), fmaxf(acc.y + b4.y, 0.f),
                      fmaxf(acc.z + b4.z, 0.f), fmaxf(acc.w + b4.w, 0.f)};
        float m = fmaxf(fmaxf(v[0], v[1]), fmaxf(v[2], v[3]));
        #pragma unroll
        for (int mask = 16; mask > 0; mask >>= 1) m = fmaxf(m, __shfl_xor(m, mask, 64));
        float sum = 0.f;
        #pragma unroll
        for (int j = 0; j < 4; ++j) {
            v[j] = __expf(v[j] - m);
            sum += v[j];
        }
        #pragma unroll
        for (int mask = 16; mask > 0; mask >>= 1) sum += __shfl_xor(sum, mask, 64);
        float inv = 1.0f / sum;
        if (half == 0)
            *(float4*)(out + (size_t)n * 128 + c0) = make_float4(v[0] * inv, v[1] * inv, v[2] * inv, v[3] * inv);
    } else {
        if (half == 0)
            *(float4*)(out + (size_t)n * 128 + c0) = acc;
    }
}

// ---------------- aggregation, DOUT=64: quarter-wave (16 lanes x float4) per edge ----------------
// input h' rows already scaled by dis[src]; out = softmax(relu(dis[n]*sum + bias))

__global__ __launch_bounds__(256) void k_agg64(const float* __restrict__ h, const int* __restrict__ off,
                                               const int* __restrict__ ss, const float* __restrict__ dis,
                                               const float* __restrict__ bias, float* __restrict__ out) {
    int lane = threadIdx.x & 63;
    int sub = lane >> 4;
    int li = lane & 15;
    int c0 = 4 * li;
    int n = blockIdx.x * 4 + (threadIdx.x >> 6);
    int e0 = off[n], e1 = off[n + 1];
    int e = e0;
    float4 acc = make_float4(0.f, 0.f, 0.f, 0.f);

    for (; e + 8 <= e1; e += 8) {
        int s0 = ss[e + sub];
        int s1 = ss[e + 4 + sub];
        float4 v0 = *(const float4*)(h + (size_t)s0 * 64 + c0);
        float4 v1 = *(const float4*)(h + (size_t)s1 * 64 + c0);
        acc.x += v0.x; acc.y += v0.y; acc.z += v0.z; acc.w += v0.w;
        acc.x += v1.x; acc.y += v1.y; acc.z += v1.z; acc.w += v1.w;
    }
    for (; e + 4 <= e1; e += 4) {
        int s = ss[e + sub];
        float4 v = *(const float4*)(h + (size_t)s * 64 + c0);
        acc.x += v.x; acc.y += v.y; acc.z += v.z; acc.w += v.w;
    }
    int rem = e1 - e;
    if (rem > 0) {
        int idx = e + sub;
        if (idx >= e1) idx = e1 - 1;
        int s = ss[idx];
        float4 v = *(const float4*)(h + (size_t)s * 64 + c0);
        float w = (sub < rem) ? 1.0f : 0.0f;
        acc.x = fmaf(w, v.x, acc.x); acc.y = fmaf(w, v.y, acc.y);
        acc.z = fmaf(w, v.z, acc.z); acc.w = fmaf(w, v.w, acc.w);
    }

    // combine the 4 sub-groups
    #pragma unroll
    for (int mask = 32; mask >= 16; mask >>= 1) {
        acc.x += __shfl_xor(acc.x, mask, 64);
        acc.y += __shfl_xor(acc.y, mask, 64);
        acc.z += __shfl_xor(acc.z, mask, 64);
        acc.w += __shfl_xor(acc.w, mask, 64);
    }

    float dn = dis[n];
    float4 b4 = *(const float4*)(bias + c0);
    float v[4] = {fmaxf(fmaf(acc.x, dn, b4.x), 0.f), fmaxf(fmaf(acc.y, dn, b4.y), 0.f),
                  fmaxf(fmaf(acc.z, dn, b4.z), 0.f), fmaxf(fmaf(acc.w, dn, b4.w), 0.f)};
    float m = fmaxf(fmaxf(v[0], v[1]), fmaxf(v[2], v[3]));
    #pragma unroll
    for (int mask = 8; mask > 0; mask >>= 1) m = fmaxf(m, __shfl_xor(m, mask, 64));
    float sum = 0.f;
    #pragma unroll
    for (int j = 0; j < 4; ++j) {
        v[j] = __expf(v[j] - m);
        sum += v[j];
    }
    #pragma unroll
    for (int mask = 8; mask > 0; mask >>= 1) sum += __shfl_xor(sum, mask, 64);
    float inv = 1.0f / sum;
    if (sub == 0)
        *(float4*)(out + (size_t)n * 64 + c0) = make_float4(v[0] * inv, v[1] * inv, v[2] * inv, v[3] * inv);
}

// ---------------- launch ----------------

extern "C" void kernel_launch(void* const* d_in, const int* in_sizes, int n_in,
                              void* d_out, int out_size, void* d_ws, size_t ws_size,
                              hipStream_t stream) {
    const float* x  = (const float*)d_in[0];
    const int*   ei = (const int*)d_in[1];
    const float* W1 = (const float*)d_in[2];
    const float* b1 = (const float*)d_in[3];
    const float* W2 = (const float*)d_in[4];
    const float* b2 = (const float*)d_in[5];
    const float* W3 = (const float*)d_in[6];
    const float* b3 = (const float*)d_in[7];
    const int* srcE = ei;
    const int* dstE = ei + N_EDGES;

    char* p = (char*)d_ws;
    auto carve = [&](size_t bytes) {
        char* q = p;
        p += (bytes + 255) & ~(size_t)255;
        return q;
    };
    int*   deg   = (int*)carve(sizeof(int) * N_NODES);
    int*   off   = (int*)carve(sizeof(int) * (N_NODES + 1));
    int*   cur   = (int*)carve(sizeof(int) * N_NODES);
    float* dis   = (float*)carve(sizeof(float) * N_NODES);
    int*   bsum  = (int*)carve(sizeof(int) * 256);
    int*   ssort = (int*)carve(sizeof(int) * E_TOT);
    short* w1h   = (short*)carve(sizeof(short) * 128 * 256);
    short* w1l   = (short*)carve(sizeof(short) * 128 * 256);
    short* w2h   = (short*)carve(sizeof(short) * 256 * 128);
    short* w2l   = (short*)carve(sizeof(short) * 256 * 128);
    short* w3h   = (short*)carve(sizeof(short) * 128 * 64);
    short* w3l   = (short*)carve(sizeof(short) * 128 * 64);
    float* bufA  = (float*)carve(sizeof(float) * (size_t)N_NODES * 256);
    float* bufB  = (float*)carve(sizeof(float) * (size_t)N_NODES * 256);

    k_init_deg<<<N_NODES / 256, 256, 0, stream>>>(deg);
    k_hist<<<(N_EDGES + 255) / 256, 256, 0, stream>>>(dstE, deg);
    k_scan1<<<N_NODES / 256, 256, 0, stream>>>(deg, off, bsum);
    k_scan2<<<1, 256, 0, stream>>>(bsum);
    k_scan3<<<N_NODES / 256, 256, 0, stream>>>(deg, off, cur, dis, bsum);
    k_scatter<<<(E_TOT + 255) / 256, 256, 0, stream>>>(srcE, dstE, cur, ssort);
    k_convw<<<(16 * 4 * 64 + 255) / 256, 256, 0, stream>>>(W1, 128, 256, w1h, w1l);
    k_convw<<<(8 * 8 * 64 + 255) / 256, 256, 0, stream>>>(W2, 256, 128, w2h, w2l);
    k_convw<<<(4 * 4 * 64 + 255) / 256, 256, 0, stream>>>(W3, 128, 64, w3h, w3l);

    // layer 1 (agg-first): a0[n] = dis[n] * sum dis[s]*x[s]; x1 = softmax(relu(a0@W1 + b1))
    k_agg128<true, false><<<N_NODES / 4, 256, 0, stream>>>(x, off, ssort, dis, nullptr, bufB);
    k_mm<128, 256, true, false><<<N_NODES / 64, 256, 0, stream>>>(bufB, w1h, w1l, b1, nullptr, bufA);
    // layer 2: h2' = dis .* (x1@W2); x2 = softmax(relu(dis[n]*segsum(h2') + b2))
    k_mm<256, 128, false, true><<<N_NODES / 64, 256, 0, stream>>>(bufA, w2h, w2l, nullptr, dis, bufB);
    k_agg128<false, true><<<N_NODES / 4, 256, 0, stream>>>(bufB, off, ssort, dis, b2, bufA);
    // layer 3: h3' = dis .* (x2@W3); out = softmax(relu(dis[n]*segsum(h3') + b3))
    k_mm<128, 64, false, true><<<N_NODES / 64, 256, 0, stream>>>(bufA, w3h, w3l, nullptr, dis, bufB);
    k_agg64<<<N_NODES / 4, 256, 0, stream>>>(bufB, off, ssort, dis, b3, (float*)d_out);
}